// Round 1
// baseline (479.983 us; speedup 1.0000x reference)
//
#include <hip/hip_runtime.h>
#include <stdint.h>

#define N_SITES 100000
#define CIN 64
#define CMID 384
#define COUT 64
#define SHIFT 16

// ---------------------------------------------------------------------------
// K1: 1x1 expand  (feats[N,64] @ w1[64,384]) + quant/relu -> x1 int8 [N+1,384]
// block = 384 threads (thread = output channel), 16 sites per block.
// fp32 FMA is exact here (|psum| <= 2^20 < 2^24).
// ---------------------------------------------------------------------------
__global__ __launch_bounds__(384) void k1_expand(
    const float* __restrict__ feats, const float* __restrict__ w1,
    const float* __restrict__ b1, const float* __restrict__ s1,
    int8_t* __restrict__ x1s)
{
    __shared__ float ftile[16][CIN];      // 4 KB
    const int c = threadIdx.x;            // 0..383
    const int site0 = blockIdx.x * 16;

    // zero the sentinel row (missing-neighbor row) once; K2 runs after K1.
    if (blockIdx.x == 0) x1s[(size_t)N_SITES * CMID + c] = 0;

    // register-cache this thread's w1 column (values are small ints, exact in f32)
    float wc[CIN];
#pragma unroll
    for (int k = 0; k < CIN; ++k) wc[k] = w1[k * CMID + c];
    const int bi = __float2int_rn(b1[c]);
    const int si = __float2int_rn(s1[c]);

    const int nsite = min(16, N_SITES - site0);
    // cooperative, coalesced load of the feats tile
    for (int i = threadIdx.x; i < 16 * CIN; i += 384) {
        int s = i / CIN, k = i % CIN;
        ftile[s][k] = (s < nsite) ? feats[(site0 + s) * CIN + k] : 0.f;
    }
    __syncthreads();

    for (int s = 0; s < nsite; ++s) {
        float acc = 0.f;
#pragma unroll
        for (int k = 0; k < CIN; ++k) acc = fmaf(ftile[s][k], wc[k], acc);
        int t = __float2int_rn(acc);
        t = (t + bi) * si + (1 << (SHIFT - 1));
        t >>= SHIFT;                       // arithmetic shift
        t = max(0, min(127, t));           // clip + relu
        x1s[(size_t)(site0 + s) * CMID + c] = (int8_t)t;
    }
}

// ---------------------------------------------------------------------------
// K2: 3x3 depthwise sparse conv + quant/relu -> x2 int8 [N,384]
// block = 384 threads = one site; thread = channel. 9 gathered byte loads.
// x1 (38 MB) is L3-resident.
// ---------------------------------------------------------------------------
__global__ __launch_bounds__(384) void k2_dw(
    const int8_t* __restrict__ x1s, const int* __restrict__ nbr,
    const float* __restrict__ wdw, const float* __restrict__ b2f,
    const float* __restrict__ s2f, int8_t* __restrict__ x2s)
{
    const int site = blockIdx.x;
    const int c = threadIdx.x;
    const int* nb = &nbr[site * 9];
    int acc = 0;
#pragma unroll
    for (int k = 0; k < 9; ++k) {
        int idx = nb[k];                                   // broadcast read
        int v = (int)x1s[(size_t)idx * CMID + c];          // coalesced bytes
        int w = __float2int_rn(wdw[k * CMID + c]);         // L1/L2 resident
        acc += v * w;
    }
    int t = (acc + __float2int_rn(b2f[c])) * __float2int_rn(s2f[c])
            + (1 << (SHIFT - 1));
    t >>= SHIFT;
    t = max(0, min(127, t));
    x2s[(size_t)site * CMID + c] = (int8_t)t;
}

// ---------------------------------------------------------------------------
// K3: 1x1 project (x2[N,384] @ w3[384,64]) + quant (no relu) -> out f32 [N,64]
// block = 256 threads = 4 waves; 16 sites/block. x2 tile unpacked to f32 LDS.
// thread = (site-slot = tid/64, cout = tid%64); lane-uniform LDS reads
// broadcast; w3 reads coalesced. fp32 FMA exact (|psum| < 2^23).
// ---------------------------------------------------------------------------
__global__ __launch_bounds__(256) void k3_proj(
    const int8_t* __restrict__ x2s, const float* __restrict__ w3,
    const float* __restrict__ b3f, const float* __restrict__ s3f,
    float* __restrict__ out)
{
    __shared__ float xt[16][CMID];        // 24 KB
    const int site0 = blockIdx.x * 16;
    const int nsite = min(16, N_SITES - site0);

    // cooperative load + unpack int8 -> f32 (x2 values are 0..127, unsigned ok)
    {
        const uint32_t* src = (const uint32_t*)(x2s + (size_t)site0 * CMID);
        float* xf = &xt[0][0];
        const int totalWords = nsite * CMID / 4;
        for (int i = threadIdx.x; i < 16 * CMID / 4; i += 256) {
            uint32_t w = (i < totalWords) ? src[i] : 0u;
            xf[i * 4 + 0] = (float)(w & 0xff);
            xf[i * 4 + 1] = (float)((w >> 8) & 0xff);
            xf[i * 4 + 2] = (float)((w >> 16) & 0xff);
            xf[i * 4 + 3] = (float)((w >> 24) & 0xff);
        }
    }
    __syncthreads();

    const int cout = threadIdx.x & 63;
    const int sslot = threadIdx.x >> 6;   // 0..3
    const int bo = __float2int_rn(b3f[cout]);
    const int so = __float2int_rn(s3f[cout]);

    float acc[4] = {0.f, 0.f, 0.f, 0.f};
    for (int kb = 0; kb < CMID; kb += 64) {
        float wreg[64];
#pragma unroll
        for (int kk = 0; kk < 64; ++kk) wreg[kk] = w3[(kb + kk) * COUT + cout];
#pragma unroll
        for (int kk = 0; kk < 64; ++kk) {
            float wv = wreg[kk];
#pragma unroll
            for (int j = 0; j < 4; ++j)
                acc[j] = fmaf(xt[sslot + j * 4][kb + kk], wv, acc[j]);
        }
    }
#pragma unroll
    for (int j = 0; j < 4; ++j) {
        int s = sslot + j * 4;
        if (s < nsite) {
            int t = __float2int_rn(acc[j]);
            t = (t + bo) * so + (1 << (SHIFT - 1));
            t >>= SHIFT;
            t = max(-128, min(127, t));
            out[(size_t)(site0 + s) * COUT + cout] = (float)t;
        }
    }
}

extern "C" void kernel_launch(void* const* d_in, const int* in_sizes, int n_in,
                              void* d_out, int out_size, void* d_ws, size_t ws_size,
                              hipStream_t stream) {
    const float* feats = (const float*)d_in[0];
    const float* w1    = (const float*)d_in[1];
    const float* b1    = (const float*)d_in[2];
    const float* s1    = (const float*)d_in[3];
    const float* wdw   = (const float*)d_in[4];
    const float* b2    = (const float*)d_in[5];
    const float* s2    = (const float*)d_in[6];
    const float* w3    = (const float*)d_in[7];
    const float* b3    = (const float*)d_in[8];
    const float* s3    = (const float*)d_in[9];
    const int*   nbr   = (const int*)d_in[10];
    float* out = (float*)d_out;

    int8_t* x1s = (int8_t*)d_ws;                               // (N+1)*384
    int8_t* x2s = x1s + (size_t)(N_SITES + 1) * CMID;          // N*384

    const int nb1 = (N_SITES + 15) / 16;   // 6250
    k1_expand<<<nb1, 384, 0, stream>>>(feats, w1, b1, s1, x1s);
    k2_dw<<<N_SITES, 384, 0, stream>>>(x1s, nbr, wdw, b2, s2, x2s);
    k3_proj<<<nb1, 256, 0, stream>>>(x2s, w3, b3, s3, out);
}

// Round 2
// 167.690 us; speedup vs baseline: 2.8623x; 2.8623x over previous
//
#include <hip/hip_runtime.h>
#include <stdint.h>

#define N_SITES 100000
#define NPAD    100032   // N rounded up to multiple of 64
#define CIN 64
#define CMID 384
#define COUT 64
#define SHIFT 16

typedef int v4i __attribute__((ext_vector_type(4)));

// ---------------------------------------------------------------------------
// pack feats f32 -> int8 (values are exact small integers)
// ---------------------------------------------------------------------------
__global__ __launch_bounds__(256) void pack_feats(const float* __restrict__ f,
                                                  int8_t* __restrict__ o) {
    int i = blockIdx.x * 256 + threadIdx.x;        // dword index
    if (i >= N_SITES * CIN / 4) return;
    const float4 v = ((const float4*)f)[i];
    uint32_t w = (uint32_t)(uint8_t)(int8_t)__float2int_rn(v.x)
               | ((uint32_t)(uint8_t)(int8_t)__float2int_rn(v.y) << 8)
               | ((uint32_t)(uint8_t)(int8_t)__float2int_rn(v.z) << 16)
               | ((uint32_t)(uint8_t)(int8_t)__float2int_rn(v.w) << 24);
    ((uint32_t*)o)[i] = w;
}

// ---------------------------------------------------------------------------
// pack w1/w3 into MFMA B-fragment order + biases/scales to int + zero sentinel
// B-frag byte (lane l, byte b) of n-tile t must hold  W[(l>>4)*16 + b][t*16 + (l&15)]
// ---------------------------------------------------------------------------
__global__ __launch_bounds__(256) void pack_weights(
    const float* __restrict__ w1, const float* __restrict__ w3,
    const float* __restrict__ b1, const float* __restrict__ s1,
    const float* __restrict__ b3, const float* __restrict__ s3,
    int8_t* __restrict__ w1p, int8_t* __restrict__ w3p,
    int* __restrict__ q1, int* __restrict__ q3, int8_t* __restrict__ x1s)
{
    int o = blockIdx.x * 256 + threadIdx.x;
    if (o < 24 * 64 * 16) {                       // w1p: [t=24][l=64][b=16]
        int t = o >> 10, l = (o >> 4) & 63, b = o & 15;
        int k = ((l >> 4) << 4) + b;
        int col = t * 16 + (l & 15);
        w1p[o] = (int8_t)__float2int_rn(w1[k * CMID + col]);
    }
    int o3 = o - 24 * 64 * 16;
    if (o3 >= 0 && o3 < 6 * 4 * 64 * 16) {        // w3p: [ks=6][t=4][l=64][b=16]
        int ks = o3 >> 12, t = (o3 >> 10) & 3;
        int l = (o3 >> 4) & 63, b = o3 & 15;
        int k = ks * 64 + ((l >> 4) << 4) + b;
        int col = t * 16 + (l & 15);
        w3p[o3] = (int8_t)__float2int_rn(w3[k * COUT + col]);
    }
    if (o < CMID) {
        q1[o] = __float2int_rn(b1[o]);
        q1[CMID + o] = __float2int_rn(s1[o]);
        x1s[(size_t)N_SITES * CMID + o] = 0;      // zero the sentinel row
    }
    if (o < COUT) {
        q3[o] = __float2int_rn(b3[o]);
        q3[COUT + o] = __float2int_rn(s3[o]);
    }
}

// ---------------------------------------------------------------------------
// K1: 1x1 expand as i8 MFMA. block = 4 waves, wave = 16 sites x 384 channels.
// A-frag: lane l holds feats8[site0 + (l&15)][(l>>4)*16 .. +16]  (one K pass).
// ---------------------------------------------------------------------------
__global__ __launch_bounds__(256) void k1_mfma(
    const int8_t* __restrict__ feats8, const int8_t* __restrict__ w1p,
    const int* __restrict__ q1, int8_t* __restrict__ x1s)
{
    const int lane = threadIdx.x & 63;
    const int wave = threadIdx.x >> 6;
    const int site0 = blockIdx.x * 64 + wave * 16;
    const int row0 = site0 + ((lane >> 4) << 2);
    const v4i a = *(const v4i*)(feats8 + (size_t)(site0 + (lane & 15)) * CIN
                                + ((lane >> 4) << 4));
    const v4i* bp = (const v4i*)w1p + lane;
#pragma unroll
    for (int t = 0; t < 24; ++t) {
        v4i b = bp[t * 64];
        v4i acc = {0, 0, 0, 0};
        acc = __builtin_amdgcn_mfma_i32_16x16x64_i8(a, b, acc, 0, 0, 0);
        const int col = t * 16 + (lane & 15);
        const int bi = q1[col], si = q1[CMID + col];
#pragma unroll
        for (int r = 0; r < 4; ++r) {
            int site = row0 + r;
            if (site < N_SITES) {
                int v = (acc[r] + bi) * si + (1 << (SHIFT - 1));
                v >>= SHIFT;
                v = max(0, min(127, v));
                x1s[(size_t)site * CMID + col] = (int8_t)v;
            }
        }
    }
}

// ---------------------------------------------------------------------------
// K2: 3x3 depthwise sparse conv (unchanged, known-correct)
// ---------------------------------------------------------------------------
__global__ __launch_bounds__(384) void k2_dw(
    const int8_t* __restrict__ x1s, const int* __restrict__ nbr,
    const float* __restrict__ wdw, const float* __restrict__ b2f,
    const float* __restrict__ s2f, int8_t* __restrict__ x2s)
{
    const int site = blockIdx.x;
    const int c = threadIdx.x;
    const int* nb = &nbr[site * 9];
    int acc = 0;
#pragma unroll
    for (int k = 0; k < 9; ++k) {
        int idx = nb[k];
        int v = (int)x1s[(size_t)idx * CMID + c];
        int w = __float2int_rn(wdw[k * CMID + c]);
        acc += v * w;
    }
    int t = (acc + __float2int_rn(b2f[c])) * __float2int_rn(s2f[c])
            + (1 << (SHIFT - 1));
    t >>= SHIFT;
    t = max(0, min(127, t));
    x2s[(size_t)site * CMID + c] = (int8_t)t;
}

// ---------------------------------------------------------------------------
// K3: 1x1 project as i8 MFMA. wave = 16 sites x 64 cols, 6 K-passes of 64.
// ---------------------------------------------------------------------------
__global__ __launch_bounds__(256) void k3_mfma(
    const int8_t* __restrict__ x2s, const int8_t* __restrict__ w3p,
    const int* __restrict__ q3, float* __restrict__ out)
{
    const int lane = threadIdx.x & 63;
    const int wave = threadIdx.x >> 6;
    const int site0 = blockIdx.x * 64 + wave * 16;
    const int row0 = site0 + ((lane >> 4) << 2);
    const int8_t* xbase = x2s + (size_t)(site0 + (lane & 15)) * CMID
                          + ((lane >> 4) << 4);
    v4i acc[4] = {{0,0,0,0},{0,0,0,0},{0,0,0,0},{0,0,0,0}};
#pragma unroll
    for (int ks = 0; ks < 6; ++ks) {
        v4i a = *(const v4i*)(xbase + ks * 64);
#pragma unroll
        for (int t = 0; t < 4; ++t) {
            v4i b = *((const v4i*)w3p + (ks * 4 + t) * 64 + lane);
            acc[t] = __builtin_amdgcn_mfma_i32_16x16x64_i8(a, b, acc[t], 0, 0, 0);
        }
    }
#pragma unroll
    for (int t = 0; t < 4; ++t) {
        const int col = t * 16 + (lane & 15);
        const int bo = q3[col], so = q3[COUT + col];
#pragma unroll
        for (int r = 0; r < 4; ++r) {
            int site = row0 + r;
            if (site < N_SITES) {
                int v = (acc[t][r] + bo) * so + (1 << (SHIFT - 1));
                v >>= SHIFT;
                v = max(-128, min(127, v));
                out[(size_t)site * COUT + col] = (float)v;
            }
        }
    }
}

extern "C" void kernel_launch(void* const* d_in, const int* in_sizes, int n_in,
                              void* d_out, int out_size, void* d_ws, size_t ws_size,
                              hipStream_t stream) {
    const float* feats = (const float*)d_in[0];
    const float* w1    = (const float*)d_in[1];
    const float* b1    = (const float*)d_in[2];
    const float* s1    = (const float*)d_in[3];
    const float* wdw   = (const float*)d_in[4];
    const float* b2    = (const float*)d_in[5];
    const float* s2    = (const float*)d_in[6];
    const float* w3    = (const float*)d_in[7];
    const float* b3    = (const float*)d_in[8];
    const float* s3    = (const float*)d_in[9];
    const int*   nbr   = (const int*)d_in[10];
    float* out = (float*)d_out;

    // ws layout (feats8 aliases x2s: K1 finishes reading it before K2 writes)
    int8_t* x1s    = (int8_t*)d_ws;                    // NPAD*384
    int8_t* x2s    = x1s + (size_t)NPAD * CMID;        // NPAD*384
    int8_t* feats8 = x2s;                              // NPAD*64 (alias)
    int8_t* w1p    = x2s + (size_t)NPAD * CMID;        // 24576
    int8_t* w3p    = w1p + 24 * 64 * 16;               // 24576
    int*    q1     = (int*)(w3p + 6 * 4 * 64 * 16);    // 2*384
    int*    q3     = q1 + 2 * CMID;                    // 2*64

    pack_feats<<<(N_SITES * CIN / 4 + 255) / 256, 256, 0, stream>>>(feats, feats8);
    pack_weights<<<192, 256, 0, stream>>>(w1, w3, b1, s1, b3, s3,
                                          w1p, w3p, q1, q3, x1s);
    k1_mfma<<<NPAD / 64, 256, 0, stream>>>(feats8, w1p, q1, x1s);
    k2_dw<<<N_SITES, 384, 0, stream>>>(x1s, nbr, wdw, b2, s2, x2s);
    k3_mfma<<<NPAD / 64, 256, 0, stream>>>(x2s, w3p, q3, out);
}

// Round 3
// 90.746 us; speedup vs baseline: 5.2893x; 1.8479x over previous
//
#include <hip/hip_runtime.h>
#include <stdint.h>

#define N_SITES 100000
#define NPAD    100032   // N rounded up to multiple of 64
#define CIN 64
#define CMID 384
#define COUT 64
#define SHIFT 16

typedef int  v4i __attribute__((ext_vector_type(4)));
typedef unsigned int v4u __attribute__((ext_vector_type(4)));

// ---------------------------------------------------------------------------
// pack feats f32 -> int8 (values are exact small integers)
// ---------------------------------------------------------------------------
__global__ __launch_bounds__(256) void pack_feats(const float* __restrict__ f,
                                                  int8_t* __restrict__ o) {
    int i = blockIdx.x * 256 + threadIdx.x;        // dword index
    if (i >= N_SITES * CIN / 4) return;
    const float4 v = ((const float4*)f)[i];
    uint32_t w = (uint32_t)(uint8_t)(int8_t)__float2int_rn(v.x)
               | ((uint32_t)(uint8_t)(int8_t)__float2int_rn(v.y) << 8)
               | ((uint32_t)(uint8_t)(int8_t)__float2int_rn(v.z) << 16)
               | ((uint32_t)(uint8_t)(int8_t)__float2int_rn(v.w) << 24);
    ((uint32_t*)o)[i] = w;
}

// ---------------------------------------------------------------------------
// pack w1/w3 into MFMA B-fragment order, wdw -> int8 [9][384],
// b2/s2 -> packed int (b low16, s high16), biases/scales to int, zero sentinel
// ---------------------------------------------------------------------------
__global__ __launch_bounds__(256) void pack_weights(
    const float* __restrict__ w1, const float* __restrict__ w3,
    const float* __restrict__ b1, const float* __restrict__ s1,
    const float* __restrict__ b2, const float* __restrict__ s2,
    const float* __restrict__ b3, const float* __restrict__ s3,
    const float* __restrict__ wdw,
    int8_t* __restrict__ w1p, int8_t* __restrict__ w3p,
    int* __restrict__ q1, int* __restrict__ q3,
    int8_t* __restrict__ wdw8, int* __restrict__ bs2,
    int8_t* __restrict__ x1s)
{
    int o = blockIdx.x * 256 + threadIdx.x;
    if (o < 24 * 64 * 16) {                       // w1p: [t=24][l=64][b=16]
        int t = o >> 10, l = (o >> 4) & 63, b = o & 15;
        int k = ((l >> 4) << 4) + b;
        int col = t * 16 + (l & 15);
        w1p[o] = (int8_t)__float2int_rn(w1[k * CMID + col]);
    }
    int o3 = o - 24 * 64 * 16;
    if (o3 >= 0 && o3 < 6 * 4 * 64 * 16) {        // w3p: [ks=6][t=4][l=64][b=16]
        int ks = o3 >> 12, t = (o3 >> 10) & 3;
        int l = (o3 >> 4) & 63, b = o3 & 15;
        int k = ks * 64 + ((l >> 4) << 4) + b;
        int col = t * 16 + (l & 15);
        w3p[o3] = (int8_t)__float2int_rn(w3[k * COUT + col]);
    }
    if (o < 9 * CMID)                              // wdw8: same [k][c] layout
        wdw8[o] = (int8_t)__float2int_rn(wdw[o]);
    if (o < CMID) {
        q1[o] = __float2int_rn(b1[o]);
        q1[CMID + o] = __float2int_rn(s1[o]);
        int bb = __float2int_rn(b2[o]);            // [-1024,1024] fits i16
        int ss = __float2int_rn(s2[o]);            // [1,64]
        bs2[o] = (bb & 0xFFFF) | (ss << 16);
        x1s[(size_t)N_SITES * CMID + o] = 0;       // zero the sentinel row
    }
    if (o < COUT) {
        q3[o] = __float2int_rn(b3[o]);
        q3[COUT + o] = __float2int_rn(s3[o]);
    }
}

// ---------------------------------------------------------------------------
// K1: 1x1 expand as i8 MFMA. block = 4 waves, wave = 16 sites x 384 channels.
// ---------------------------------------------------------------------------
__global__ __launch_bounds__(256) void k1_mfma(
    const int8_t* __restrict__ feats8, const int8_t* __restrict__ w1p,
    const int* __restrict__ q1, int8_t* __restrict__ x1s)
{
    const int lane = threadIdx.x & 63;
    const int wave = threadIdx.x >> 6;
    const int site0 = blockIdx.x * 64 + wave * 16;
    const int row0 = site0 + ((lane >> 4) << 2);
    const v4i a = *(const v4i*)(feats8 + (size_t)(site0 + (lane & 15)) * CIN
                                + ((lane >> 4) << 4));
    const v4i* bp = (const v4i*)w1p + lane;
#pragma unroll
    for (int t = 0; t < 24; ++t) {
        v4i b = bp[t * 64];
        v4i acc = {0, 0, 0, 0};
        acc = __builtin_amdgcn_mfma_i32_16x16x64_i8(a, b, acc, 0, 0, 0);
        const int col = t * 16 + (lane & 15);
        const int bi = q1[col], si = q1[CMID + col];
#pragma unroll
        for (int r = 0; r < 4; ++r) {
            int site = row0 + r;
            if (site < N_SITES) {
                int v = (acc[r] + bi) * si + (1 << (SHIFT - 1));
                v >>= SHIFT;
                v = max(0, min(127, v));
                x1s[(size_t)site * CMID + col] = (int8_t)v;
            }
        }
    }
}

// ---------------------------------------------------------------------------
// K2: 3x3 depthwise. thread = 16 channels of one site; 24 chunks/site.
// 9 dwordx4 gathers + int8 weight dwordx4 (L1-hot); v_mad_i32_i24 MACs.
// tasks = 100000*24 = 2,400,000 = 9375 blocks * 256 exactly.
// ---------------------------------------------------------------------------
__global__ __launch_bounds__(256) void k2_dw(
    const int8_t* __restrict__ x1s, const int* __restrict__ nbr,
    const int8_t* __restrict__ wdw8, const int* __restrict__ bs2,
    int8_t* __restrict__ x2s)
{
    const int g = blockIdx.x * 256 + threadIdx.x;
    const int site = g / 24;
    const int c0 = (g - site * 24) << 4;           // channel base, 0..368

    const int* nb = &nbr[site * 9];
    int idx[9];
#pragma unroll
    for (int k = 0; k < 9; ++k) idx[k] = nb[k];

    v4u V[9];
#pragma unroll
    for (int k = 0; k < 9; ++k) {
        const int off = (idx[k] << 8) + (idx[k] << 7) + c0;   // idx*384 + c0
        V[k] = *(const v4u*)(x1s + off);
    }

    int acc[16];
#pragma unroll
    for (int j = 0; j < 16; ++j) acc[j] = 0;

#pragma unroll
    for (int k = 0; k < 9; ++k) {
        const v4u W = *(const v4u*)(wdw8 + k * CMID + c0);
#pragma unroll
        for (int j = 0; j < 4; ++j) {
#pragma unroll
            for (int b = 0; b < 4; ++b) {
                const int v = (int)(uint8_t)(V[k][j] >> (8 * b));  // [0,127]
                const int w = (int)(int8_t)(W[j] >> (8 * b));      // [-128,127]
                acc[j * 4 + b] += v * w;           // v_mad_i32_i24
            }
        }
    }

    const v4i BS0 = *(const v4i*)(bs2 + c0);
    const v4i BS1 = *(const v4i*)(bs2 + c0 + 4);
    const v4i BS2 = *(const v4i*)(bs2 + c0 + 8);
    const v4i BS3 = *(const v4i*)(bs2 + c0 + 12);
    const v4i BS[4] = {BS0, BS1, BS2, BS3};

    v4u outw;
#pragma unroll
    for (int j = 0; j < 4; ++j) {
        uint32_t wrd = 0;
#pragma unroll
        for (int b = 0; b < 4; ++b) {
            const int bsv = BS[j][b];
            const int bb = (bsv << 16) >> 16;      // sext low 16
            const int ss = bsv >> 16;              // sext high 16
            int t = ((acc[j * 4 + b] + bb) * ss + (1 << (SHIFT - 1))) >> SHIFT;
            t = max(0, min(127, t));
            wrd |= (uint32_t)t << (8 * b);
        }
        outw[j] = wrd;
    }
    *(v4u*)(x2s + (site << 8) + (site << 7) + c0) = outw;
}

// ---------------------------------------------------------------------------
// K3: 1x1 project as i8 MFMA. wave = 16 sites x 64 cols, 6 K-passes of 64.
// ---------------------------------------------------------------------------
__global__ __launch_bounds__(256) void k3_mfma(
    const int8_t* __restrict__ x2s, const int8_t* __restrict__ w3p,
    const int* __restrict__ q3, float* __restrict__ out)
{
    const int lane = threadIdx.x & 63;
    const int wave = threadIdx.x >> 6;
    const int site0 = blockIdx.x * 64 + wave * 16;
    const int row0 = site0 + ((lane >> 4) << 2);
    const int8_t* xbase = x2s + (size_t)(site0 + (lane & 15)) * CMID
                          + ((lane >> 4) << 4);
    v4i acc[4] = {{0,0,0,0},{0,0,0,0},{0,0,0,0},{0,0,0,0}};
#pragma unroll
    for (int ks = 0; ks < 6; ++ks) {
        v4i a = *(const v4i*)(xbase + ks * 64);
#pragma unroll
        for (int t = 0; t < 4; ++t) {
            v4i b = *((const v4i*)w3p + (ks * 4 + t) * 64 + lane);
            acc[t] = __builtin_amdgcn_mfma_i32_16x16x64_i8(a, b, acc[t], 0, 0, 0);
        }
    }
#pragma unroll
    for (int t = 0; t < 4; ++t) {
        const int col = t * 16 + (lane & 15);
        const int bo = q3[col], so = q3[COUT + col];
#pragma unroll
        for (int r = 0; r < 4; ++r) {
            int site = row0 + r;
            if (site < N_SITES) {
                int v = (acc[t][r] + bo) * so + (1 << (SHIFT - 1));
                v >>= SHIFT;
                v = max(-128, min(127, v));
                out[(size_t)site * COUT + col] = (float)v;
            }
        }
    }
}

extern "C" void kernel_launch(void* const* d_in, const int* in_sizes, int n_in,
                              void* d_out, int out_size, void* d_ws, size_t ws_size,
                              hipStream_t stream) {
    const float* feats = (const float*)d_in[0];
    const float* w1    = (const float*)d_in[1];
    const float* b1    = (const float*)d_in[2];
    const float* s1    = (const float*)d_in[3];
    const float* wdw   = (const float*)d_in[4];
    const float* b2    = (const float*)d_in[5];
    const float* s2    = (const float*)d_in[6];
    const float* w3    = (const float*)d_in[7];
    const float* b3    = (const float*)d_in[8];
    const float* s3    = (const float*)d_in[9];
    const int*   nbr   = (const int*)d_in[10];
    float* out = (float*)d_out;

    // ws layout (feats8 aliases x2s: K1 finishes reading it before K2 writes)
    int8_t* x1s    = (int8_t*)d_ws;                    // NPAD*384
    int8_t* x2s    = x1s + (size_t)NPAD * CMID;        // NPAD*384
    int8_t* feats8 = x2s;                              // NPAD*64 (alias)
    int8_t* w1p    = x2s + (size_t)NPAD * CMID;        // 24576
    int8_t* w3p    = w1p + 24 * 64 * 16;               // 24576
    int*    q1     = (int*)(w3p + 6 * 4 * 64 * 16);    // 2*384 ints
    int*    q3     = q1 + 2 * CMID;                    // 2*64 ints
    int8_t* wdw8   = (int8_t*)(q3 + 2 * COUT);         // 9*384 bytes
    int*    bs2    = (int*)(wdw8 + 9 * CMID);          // 384 ints

    pack_feats<<<(N_SITES * CIN / 4 + 255) / 256, 256, 0, stream>>>(feats, feats8);
    pack_weights<<<192, 256, 0, stream>>>(w1, w3, b1, s1, b2, s2, b3, s3, wdw,
                                          w1p, w3p, q1, q3, wdw8, bs2, x1s);
    k1_mfma<<<NPAD / 64, 256, 0, stream>>>(feats8, w1p, q1, x1s);
    k2_dw<<<N_SITES * 24 / 256, 256, 0, stream>>>(x1s, nbr, wdw8, bs2, x2s);
    k3_mfma<<<NPAD / 64, 256, 0, stream>>>(x2s, w3p, q3, out);
}